// Round 2
// baseline (703.300 us; speedup 1.0000x reference)
//
#include <hip/hip_runtime.h>
#include <hip/hip_bf16.h>

typedef unsigned short u16;

#define M_ROWS 8192
#define N_ROWS 16384
#define KDIM   512
#define BM     128
#define BN     128
#define BK     64
#define NCHUNKS 16
#define NPER   (N_ROWS / NCHUNKS)   /* 1024 */
#define TOPK   9

typedef __attribute__((ext_vector_type(8))) short bf16x8;
typedef __attribute__((ext_vector_type(4))) float f32x4;

__device__ __forceinline__ void gload_lds16(const void* g, void* l) {
  __builtin_amdgcn_global_load_lds(
      (const __attribute__((address_space(1))) void*)g,
      (__attribute__((address_space(3))) void*)l,
      16, 0, 0);
}

__device__ __forceinline__ u16 f2bf(float x) {
  union { float f; unsigned u; } c; c.f = x;
  unsigned u = c.u;
  u += 0x7fffu + ((u >> 16) & 1u);   // RNE; inputs finite randn
  return (u16)(u >> 16);
}

__device__ __forceinline__ void topk_update(float v, float best[TOPK]) {
  if (v < best[TOPK - 1]) {
    #pragma unroll
    for (int i = 0; i < TOPK; ++i) {
      float b = best[i];
      best[i] = fminf(b, v);
      v = fmaxf(b, v);
    }
  }
}

// ---------------- Kernel 1: fp32 -> bf16 convert + fp32 row norms (wave/row) ----------------
__global__ __launch_bounds__(256) void prep_kernel(
    const float* __restrict__ fv, const float* __restrict__ mb,
    u16* __restrict__ fvb, u16* __restrict__ mbb,
    float* __restrict__ nf, float* __restrict__ nm)
{
  int idx = blockIdx.x * 4 + (threadIdx.x >> 6);   // one wave per row
  int l = threadIdx.x & 63;
  const float* src; u16* dst; float* nrm;
  if (idx < M_ROWS) {
    src = fv + (size_t)idx * KDIM; dst = fvb + (size_t)idx * KDIM; nrm = nf + idx;
  } else {
    int r = idx - M_ROWS;
    src = mb + (size_t)r * KDIM; dst = mbb + (size_t)r * KDIM; nrm = nm + r;
  }
  float4 x0 = ((const float4*)src)[2 * l];
  float4 x1 = ((const float4*)src)[2 * l + 1];
  float s = x0.x * x0.x + x0.y * x0.y + x0.z * x0.z + x0.w * x0.w
          + x1.x * x1.x + x1.y * x1.y + x1.z * x1.z + x1.w * x1.w;
  uint4 o;
  o.x = (unsigned)f2bf(x0.x) | ((unsigned)f2bf(x0.y) << 16);
  o.y = (unsigned)f2bf(x0.z) | ((unsigned)f2bf(x0.w) << 16);
  o.z = (unsigned)f2bf(x1.x) | ((unsigned)f2bf(x1.y) << 16);
  o.w = (unsigned)f2bf(x1.z) | ((unsigned)f2bf(x1.w) << 16);
  ((uint4*)dst)[l] = o;
  #pragma unroll
  for (int off = 32; off > 0; off >>= 1) s += __shfl_down(s, off, 64);
  if (l == 0) nrm[0] = s;
}

// ------------- Kernel 2: bf16 MFMA GEMM (swapped operands) + register top-9 -------------
// grid (64, 16), block 256 (4 waves). Block: 128 fv-rows (m) x 1024 mb-rows (n).
// C[row=n][col=m]; each thread covers 4 m-rows (lists), 16 n-values each per n-tile.
// Ranked value v = nm[n] - 2*dot (nf[m] constant per list -> deferred).
__global__ __launch_bounds__(256, 3) void gemm_topk_kernel(
    const u16* __restrict__ fvb, const u16* __restrict__ mbb,
    const float* __restrict__ nm, float* __restrict__ partial)
{
  __shared__ __align__(16) u16 As[BM * BK];     // fv tile   [128][64], 16 KB
  __shared__ __align__(16) u16 Bs[BN * BK];     // mb tile   [128][64], 16 KB

  const int t    = threadIdx.x;
  const int l    = t & 63;
  const int w    = t >> 6;
  const int nq   = w & 1;        // wave n-quadrant (C rows)
  const int mq   = w >> 1;       // wave m-quadrant (C cols)
  const int quad = l >> 4;
  const int l15  = l & 15;

  const int m0    = blockIdx.x * BM;
  const int ncoff = blockIdx.y * NPER;

  const int srow = w * 32 + (l >> 3);
  const int scol = (l & 7) * 8;

  float best[4][TOPK];
  float T[4];
  #pragma unroll
  for (int j = 0; j < 4; ++j) {
    T[j] = 3.4e38f;
    #pragma unroll
    for (int i = 0; i < TOPK; ++i) best[j][i] = 3.4e38f;
  }

  for (int nt = 0; nt < NPER / BN; ++nt) {
    const int nbase = ncoff + nt * BN;
    f32x4 acc[4][4];   // acc[i][j]: i = n-subtile, j = m-subtile
    #pragma unroll
    for (int i = 0; i < 4; ++i)
      #pragma unroll
      for (int j = 0; j < 4; ++j) acc[i][j] = (f32x4){0.f, 0.f, 0.f, 0.f};

    for (int kc = 0; kc < KDIM / BK; ++kc) {
      __syncthreads();
      const int kb = kc * BK + scol;
      #pragma unroll
      for (int i = 0; i < 4; ++i) {
        gload_lds16(fvb + (size_t)(m0 + srow + i * 8) * KDIM + kb,
                    &As[(w * 32 + i * 8) * BK]);
        gload_lds16(mbb + (size_t)(nbase + srow + i * 8) * KDIM + kb,
                    &Bs[(w * 32 + i * 8) * BK]);
      }
      __syncthreads();
      #pragma unroll
      for (int ks = 0; ks < 2; ++ks) {
        bf16x8 af[4], bf[4];
        #pragma unroll
        for (int i = 0; i < 4; ++i) {
          af[i] = *(const bf16x8*)&Bs[(nq * 64 + i * 16 + l15) * BK + ks * 32 + quad * 8];
          bf[i] = *(const bf16x8*)&As[(mq * 64 + i * 16 + l15) * BK + ks * 32 + quad * 8];
        }
        #pragma unroll
        for (int i = 0; i < 4; ++i)
          #pragma unroll
          for (int j = 0; j < 4; ++j)
            acc[i][j] = __builtin_amdgcn_mfma_f32_16x16x32_bf16(af[i], bf[j], acc[i][j], 0, 0, 0);
      }
    }

    // ---- register epilogue: batch-min prefilter + rare sorted insert ----
    float nmr[16];
    #pragma unroll
    for (int i = 0; i < 4; ++i) {
      float4 t4 = *(const float4*)&nm[nbase + nq * 64 + i * 16 + quad * 4];
      nmr[i * 4 + 0] = t4.x; nmr[i * 4 + 1] = t4.y;
      nmr[i * 4 + 2] = t4.z; nmr[i * 4 + 3] = t4.w;
    }
    #pragma unroll
    for (int j = 0; j < 4; ++j) {
      float v[16];
      float bmin = 3.4e38f;
      #pragma unroll
      for (int i = 0; i < 4; ++i)
        #pragma unroll
        for (int r = 0; r < 4; ++r) {
          float x = fmaf(-2.0f, acc[i][j][r], nmr[i * 4 + r]);
          v[i * 4 + r] = x;
          bmin = fminf(bmin, x);
        }
      if (bmin < T[j]) {
        #pragma unroll
        for (int e = 0; e < 16; ++e) topk_update(v[e], best[j]);
      }
    }
    // refresh shared thresholds across the 4 quads holding the same m-row
    #pragma unroll
    for (int j = 0; j < 4; ++j) {
      float th = best[j][TOPK - 1];
      th = fminf(th, __shfl_xor(th, 16, 64));
      th = fminf(th, __shfl_xor(th, 32, 64));
      T[j] = th;
    }
  }

  // ---- butterfly-merge the 4 quads' lists (snapshot per round), write partials ----
  #pragma unroll
  for (int j = 0; j < 4; ++j) {
    #pragma unroll
    for (int off = 16; off <= 32; off <<= 1) {
      float tmp[TOPK];
      #pragma unroll
      for (int s = 0; s < TOPK; ++s) tmp[s] = __shfl_xor(best[j][s], off, 64);
      #pragma unroll
      for (int s = 0; s < TOPK; ++s) topk_update(tmp[s], best[j]);
    }
  }
  #pragma unroll
  for (int j = 0; j < 4; ++j) {
    int grow = m0 + mq * 64 + j * 16 + l15;
    size_t base = ((size_t)(blockIdx.y * 2 + nq) * M_ROWS + grow) * TOPK;
    if (quad < 3) {
      #pragma unroll
      for (int s = 0; s < 3; ++s) partial[base + quad * 3 + s] = best[j][quad * 3 + s];
    }
  }
}

// ---------------- Kernel 3: merge 32 partial lists/row, sqrt, pixel scores ----------------
__global__ __launch_bounds__(256) void merge_kernel(
    const float* __restrict__ partial, const float* __restrict__ nf,
    float* __restrict__ final9, float* __restrict__ out_pix)
{
  int row = blockIdx.x * 256 + threadIdx.x;   // 8192 rows
  float best[TOPK];
  #pragma unroll
  for (int i = 0; i < TOPK; ++i) best[i] = 3.4e38f;
  for (int s = 0; s < 2 * NCHUNKS; ++s) {
    const float* p = &partial[((size_t)s * M_ROWS + row) * TOPK];
    #pragma unroll
    for (int i = 0; i < TOPK; ++i) topk_update(p[i], best);
  }
  float nfr = nf[row];
  float d[TOPK];
  #pragma unroll
  for (int i = 0; i < TOPK; ++i) d[i] = sqrtf(fmaxf(best[i] + nfr, 0.0f));
  out_pix[row] = d[0];
  #pragma unroll
  for (int i = 0; i < TOPK; ++i) final9[(size_t)row * TOPK + i] = d[i];
}

// ---------------- Kernel 4: per-image argmax (first-max) + softmax score ----------------
__global__ __launch_bounds__(256) void img_kernel(
    const float* __restrict__ out_pix, const float* __restrict__ final9,
    const int* __restrict__ bptr, float* __restrict__ out_img)
{
  int img = blockIdx.x, t = threadIdx.x;
  float bv = -1.0f; int bi = 0;
  for (int p = t; p < 1024; p += 256) {
    float v = out_pix[img * 1024 + p];
    if (v > bv) { bv = v; bi = p; }
  }
  __shared__ float sv[256];
  __shared__ int   si[256];
  sv[t] = bv; si[t] = bi;
  __syncthreads();
  for (int off = 128; off > 0; off >>= 1) {
    if (t < off) {
      float v2 = sv[t + off]; int i2 = si[t + off];
      if (v2 > sv[t] || (v2 == sv[t] && i2 < si[t])) { sv[t] = v2; si[t] = i2; }
    }
    __syncthreads();
  }
  if (t == 0) {
    int row = img * 1024 + si[0];
    int b = bptr[0];
    float s0 = final9[(size_t)row * TOPK + 0];
    float score = s0;
    if (b > 1) {
      int bb = b < TOPK ? b : TOPK;
      float mx = s0;
      for (int i = 1; i < bb; ++i) mx = fmaxf(mx, final9[(size_t)row * TOPK + i]);
      float den = 0.0f;
      for (int i = 0; i < bb; ++i) den += expf(final9[(size_t)row * TOPK + i] - mx);
      score = s0 * (1.0f - expf(s0 - mx) / den);
    }
    out_img[img] = score;
  }
}

extern "C" void kernel_launch(void* const* d_in, const int* in_sizes, int n_in,
                              void* d_out, int out_size, void* d_ws, size_t ws_size,
                              hipStream_t stream) {
  const float* fv   = (const float*)d_in[0];
  const float* mb   = (const float*)d_in[1];
  const int*   bptr = (const int*)d_in[2];
  float* out = (float*)d_out;

  char* w = (char*)d_ws;
  u16*   fvb     = (u16*)w;                        // 8388608 B
  u16*   mbb     = (u16*)(w + 8388608);            // 16777216 B
  float* nf      = (float*)(w + 25165824);         // 32768 B
  float* nm      = (float*)(w + 25198592);         // 65536 B
  float* partial = (float*)(w + 25264128);         // 32*8192*9*4 = 9437184 B
  float* final9  = (float*)(w + 34701312);         // 294912 B  (end ~35.0 MB)

  hipLaunchKernelGGL(prep_kernel, dim3((M_ROWS + N_ROWS) / 4), dim3(256), 0, stream,
                     fv, mb, fvb, mbb, nf, nm);
  hipLaunchKernelGGL(gemm_topk_kernel, dim3(M_ROWS / BM, NCHUNKS), dim3(256), 0, stream,
                     fvb, mbb, nm, partial);
  hipLaunchKernelGGL(merge_kernel, dim3(M_ROWS / 256), dim3(256), 0, stream,
                     partial, nf, final9, out);
  hipLaunchKernelGGL(img_kernel, dim3(8), dim3(256), 0, stream,
                     out, final9, bptr, out + M_ROWS);
}

// Round 3
// 612.339 us; speedup vs baseline: 1.1485x; 1.1485x over previous
//
#include <hip/hip_runtime.h>
#include <hip/hip_bf16.h>

typedef unsigned short u16;

#define M_ROWS 8192
#define N_ROWS 16384
#define KDIM   512
#define BM     128
#define BN     128
#define BK     64
#define NCHUNKS 16
#define NPER   (N_ROWS / NCHUNKS)   /* 1024 */
#define TOPK   9

typedef __attribute__((ext_vector_type(8))) short bf16x8;
typedef __attribute__((ext_vector_type(4))) float f32x4;

__device__ __forceinline__ void gload_lds16(const void* g, void* l) {
  __builtin_amdgcn_global_load_lds(
      (const __attribute__((address_space(1))) void*)g,
      (__attribute__((address_space(3))) void*)l,
      16, 0, 0);
}

__device__ __forceinline__ u16 f2bf(float x) {
  union { float f; unsigned u; } c; c.f = x;
  unsigned u = c.u;
  u += 0x7fffu + ((u >> 16) & 1u);   // RNE; inputs finite randn
  return (u16)(u >> 16);
}

__device__ __forceinline__ void topk_update(float v, float best[TOPK]) {
  if (v < best[TOPK - 1]) {
    #pragma unroll
    for (int i = 0; i < TOPK; ++i) {
      float b = best[i];
      best[i] = fminf(b, v);
      v = fmaxf(b, v);
    }
  }
}

// ---------------- Kernel 1: fp32 -> bf16 convert + fp32 row norms (wave/row) ----------------
__global__ __launch_bounds__(256) void prep_kernel(
    const float* __restrict__ fv, const float* __restrict__ mb,
    u16* __restrict__ fvb, u16* __restrict__ mbb,
    float* __restrict__ nf, float* __restrict__ nm)
{
  int idx = blockIdx.x * 4 + (threadIdx.x >> 6);   // one wave per row
  int l = threadIdx.x & 63;
  const float* src; u16* dst; float* nrm;
  if (idx < M_ROWS) {
    src = fv + (size_t)idx * KDIM; dst = fvb + (size_t)idx * KDIM; nrm = nf + idx;
  } else {
    int r = idx - M_ROWS;
    src = mb + (size_t)r * KDIM; dst = mbb + (size_t)r * KDIM; nrm = nm + r;
  }
  float4 x0 = ((const float4*)src)[2 * l];
  float4 x1 = ((const float4*)src)[2 * l + 1];
  float s = x0.x * x0.x + x0.y * x0.y + x0.z * x0.z + x0.w * x0.w
          + x1.x * x1.x + x1.y * x1.y + x1.z * x1.z + x1.w * x1.w;
  uint4 o;
  o.x = (unsigned)f2bf(x0.x) | ((unsigned)f2bf(x0.y) << 16);
  o.y = (unsigned)f2bf(x0.z) | ((unsigned)f2bf(x0.w) << 16);
  o.z = (unsigned)f2bf(x1.x) | ((unsigned)f2bf(x1.y) << 16);
  o.w = (unsigned)f2bf(x1.z) | ((unsigned)f2bf(x1.w) << 16);
  ((uint4*)dst)[l] = o;
  #pragma unroll
  for (int off = 32; off > 0; off >>= 1) s += __shfl_down(s, off, 64);
  if (l == 0) nrm[0] = s;
}

// ------------- Kernel 2: bf16 MFMA GEMM (swapped operands) + register top-9 -------------
// grid (64, 16), block 256 (4 waves). Block: 128 fv-rows (m) x 1024 mb-rows (n).
// C[row=n][col=m]; each thread covers 4 m-rows (lists), 16 n-values each per n-tile.
// Ranked value v = nm[n] - 2*dot (nf[m] constant per list -> deferred).
// launch_bounds(256,2): 256-VGPR cap. (256,3) capped at ~170 and spilled acc ->
// 826 MB scratch traffic, 604 us (R2 post-mortem). LDS 32 KB is not the binder.
__global__ __launch_bounds__(256, 2) void gemm_topk_kernel(
    const u16* __restrict__ fvb, const u16* __restrict__ mbb,
    const float* __restrict__ nm, float* __restrict__ partial)
{
  __shared__ __align__(16) u16 As[BM * BK];     // fv tile   [128][64], 16 KB
  __shared__ __align__(16) u16 Bs[BN * BK];     // mb tile   [128][64], 16 KB

  const int t    = threadIdx.x;
  const int l    = t & 63;
  const int w    = t >> 6;
  const int nq   = w & 1;        // wave n-quadrant (C rows)
  const int mq   = w >> 1;       // wave m-quadrant (C cols)
  const int quad = l >> 4;
  const int l15  = l & 15;

  const int m0    = blockIdx.x * BM;
  const int ncoff = blockIdx.y * NPER;

  const int srow = w * 32 + (l >> 3);
  const int scol = (l & 7) * 8;

  float best[4][TOPK];
  float T[4];
  #pragma unroll
  for (int j = 0; j < 4; ++j) {
    T[j] = 3.4e38f;
    #pragma unroll
    for (int i = 0; i < TOPK; ++i) best[j][i] = 3.4e38f;
  }

  for (int nt = 0; nt < NPER / BN; ++nt) {
    const int nbase = ncoff + nt * BN;
    f32x4 acc[4][4];   // acc[i][j]: i = n-subtile, j = m-subtile
    #pragma unroll
    for (int i = 0; i < 4; ++i)
      #pragma unroll
      for (int j = 0; j < 4; ++j) acc[i][j] = (f32x4){0.f, 0.f, 0.f, 0.f};

    for (int kc = 0; kc < KDIM / BK; ++kc) {
      __syncthreads();
      const int kb = kc * BK + scol;
      #pragma unroll
      for (int i = 0; i < 4; ++i) {
        gload_lds16(fvb + (size_t)(m0 + srow + i * 8) * KDIM + kb,
                    &As[(w * 32 + i * 8) * BK]);
        gload_lds16(mbb + (size_t)(nbase + srow + i * 8) * KDIM + kb,
                    &Bs[(w * 32 + i * 8) * BK]);
      }
      __syncthreads();
      #pragma unroll
      for (int ks = 0; ks < 2; ++ks) {
        bf16x8 af[4], bf[4];
        #pragma unroll
        for (int i = 0; i < 4; ++i) {
          af[i] = *(const bf16x8*)&Bs[(nq * 64 + i * 16 + l15) * BK + ks * 32 + quad * 8];
          bf[i] = *(const bf16x8*)&As[(mq * 64 + i * 16 + l15) * BK + ks * 32 + quad * 8];
        }
        #pragma unroll
        for (int i = 0; i < 4; ++i)
          #pragma unroll
          for (int j = 0; j < 4; ++j)
            acc[i][j] = __builtin_amdgcn_mfma_f32_16x16x32_bf16(af[i], bf[j], acc[i][j], 0, 0, 0);
      }
    }

    // ---- register epilogue: batch-min prefilter; rare branch recomputes from acc ----
    float nmr[16];
    #pragma unroll
    for (int i = 0; i < 4; ++i) {
      float4 t4 = *(const float4*)&nm[nbase + nq * 64 + i * 16 + quad * 4];
      nmr[i * 4 + 0] = t4.x; nmr[i * 4 + 1] = t4.y;
      nmr[i * 4 + 2] = t4.z; nmr[i * 4 + 3] = t4.w;
    }
    #pragma unroll
    for (int j = 0; j < 4; ++j) {
      float bmin = 3.4e38f;
      #pragma unroll
      for (int i = 0; i < 4; ++i)
        #pragma unroll
        for (int r = 0; r < 4; ++r)
          bmin = fminf(bmin, fmaf(-2.0f, acc[i][j][r], nmr[i * 4 + r]));
      if (bmin < T[j]) {
        #pragma unroll
        for (int i = 0; i < 4; ++i)
          #pragma unroll
          for (int r = 0; r < 4; ++r)
            topk_update(fmaf(-2.0f, acc[i][j][r], nmr[i * 4 + r]), best[j]);
      }
    }
    // refresh shared thresholds across the 4 quads holding the same m-row
    #pragma unroll
    for (int j = 0; j < 4; ++j) {
      float th = best[j][TOPK - 1];
      th = fminf(th, __shfl_xor(th, 16, 64));
      th = fminf(th, __shfl_xor(th, 32, 64));
      T[j] = th;
    }
  }

  // ---- butterfly-merge the 4 quads' lists (snapshot per round), write partials ----
  #pragma unroll
  for (int j = 0; j < 4; ++j) {
    #pragma unroll
    for (int off = 16; off <= 32; off <<= 1) {
      float tmp[TOPK];
      #pragma unroll
      for (int s = 0; s < TOPK; ++s) tmp[s] = __shfl_xor(best[j][s], off, 64);
      #pragma unroll
      for (int s = 0; s < TOPK; ++s) topk_update(tmp[s], best[j]);
    }
  }
  #pragma unroll
  for (int j = 0; j < 4; ++j) {
    int grow = m0 + mq * 64 + j * 16 + l15;
    size_t base = ((size_t)(blockIdx.y * 2 + nq) * M_ROWS + grow) * TOPK;
    if (quad < 3) {
      #pragma unroll
      for (int s = 0; s < 3; ++s) partial[base + quad * 3 + s] = best[j][quad * 3 + s];
    }
  }
}

// ---------------- Kernel 3: merge 32 partial lists/row, sqrt, pixel scores ----------------
__global__ __launch_bounds__(256) void merge_kernel(
    const float* __restrict__ partial, const float* __restrict__ nf,
    float* __restrict__ final9, float* __restrict__ out_pix)
{
  int row = blockIdx.x * 256 + threadIdx.x;   // 8192 rows
  float best[TOPK];
  #pragma unroll
  for (int i = 0; i < TOPK; ++i) best[i] = 3.4e38f;
  for (int s = 0; s < 2 * NCHUNKS; ++s) {
    const float* p = &partial[((size_t)s * M_ROWS + row) * TOPK];
    #pragma unroll
    for (int i = 0; i < TOPK; ++i) topk_update(p[i], best);
  }
  float nfr = nf[row];
  float d[TOPK];
  #pragma unroll
  for (int i = 0; i < TOPK; ++i) d[i] = sqrtf(fmaxf(best[i] + nfr, 0.0f));
  out_pix[row] = d[0];
  #pragma unroll
  for (int i = 0; i < TOPK; ++i) final9[(size_t)row * TOPK + i] = d[i];
}

// ---------------- Kernel 4: per-image argmax (first-max) + softmax score ----------------
__global__ __launch_bounds__(256) void img_kernel(
    const float* __restrict__ out_pix, const float* __restrict__ final9,
    const int* __restrict__ bptr, float* __restrict__ out_img)
{
  int img = blockIdx.x, t = threadIdx.x;
  float bv = -1.0f; int bi = 0;
  for (int p = t; p < 1024; p += 256) {
    float v = out_pix[img * 1024 + p];
    if (v > bv) { bv = v; bi = p; }
  }
  __shared__ float sv[256];
  __shared__ int   si[256];
  sv[t] = bv; si[t] = bi;
  __syncthreads();
  for (int off = 128; off > 0; off >>= 1) {
    if (t < off) {
      float v2 = sv[t + off]; int i2 = si[t + off];
      if (v2 > sv[t] || (v2 == sv[t] && i2 < si[t])) { sv[t] = v2; si[t] = i2; }
    }
    __syncthreads();
  }
  if (t == 0) {
    int row = img * 1024 + si[0];
    int b = bptr[0];
    float s0 = final9[(size_t)row * TOPK + 0];
    float score = s0;
    if (b > 1) {
      int bb = b < TOPK ? b : TOPK;
      float mx = s0;
      for (int i = 1; i < bb; ++i) mx = fmaxf(mx, final9[(size_t)row * TOPK + i]);
      float den = 0.0f;
      for (int i = 0; i < bb; ++i) den += expf(final9[(size_t)row * TOPK + i] - mx);
      score = s0 * (1.0f - expf(s0 - mx) / den);
    }
    out_img[img] = score;
  }
}

extern "C" void kernel_launch(void* const* d_in, const int* in_sizes, int n_in,
                              void* d_out, int out_size, void* d_ws, size_t ws_size,
                              hipStream_t stream) {
  const float* fv   = (const float*)d_in[0];
  const float* mb   = (const float*)d_in[1];
  const int*   bptr = (const int*)d_in[2];
  float* out = (float*)d_out;

  char* w = (char*)d_ws;
  u16*   fvb     = (u16*)w;                        // 8388608 B
  u16*   mbb     = (u16*)(w + 8388608);            // 16777216 B
  float* nf      = (float*)(w + 25165824);         // 32768 B
  float* nm      = (float*)(w + 25198592);         // 65536 B
  float* partial = (float*)(w + 25264128);         // 32*8192*9*4 = 9437184 B
  float* final9  = (float*)(w + 34701312);         // 294912 B  (end ~35.0 MB)

  hipLaunchKernelGGL(prep_kernel, dim3((M_ROWS + N_ROWS) / 4), dim3(256), 0, stream,
                     fv, mb, fvb, mbb, nf, nm);
  hipLaunchKernelGGL(gemm_topk_kernel, dim3(M_ROWS / BM, NCHUNKS), dim3(256), 0, stream,
                     fvb, mbb, nm, partial);
  hipLaunchKernelGGL(merge_kernel, dim3(M_ROWS / 256), dim3(256), 0, stream,
                     partial, nf, final9, out);
  hipLaunchKernelGGL(img_kernel, dim3(8), dim3(256), 0, stream,
                     out, final9, bptr, out + M_ROWS);
}

// Round 4
// 314.127 us; speedup vs baseline: 2.2389x; 1.9493x over previous
//
#include <hip/hip_runtime.h>
#include <hip/hip_bf16.h>

typedef unsigned short u16;

#define M_ROWS 8192
#define N_ROWS 16384
#define KDIM   512
#define BM     128
#define BN     128
#define BK     64
#define NCHUNKS 8
#define NPER   (N_ROWS / NCHUNKS)   /* 2048 */
#define TOPK   9

typedef __attribute__((ext_vector_type(8)))  short bf16x8;
typedef __attribute__((ext_vector_type(16))) float f32x16;

__device__ __forceinline__ void gload_lds16(const void* g, void* l) {
  __builtin_amdgcn_global_load_lds(
      (const __attribute__((address_space(1))) void*)g,
      (__attribute__((address_space(3))) void*)l,
      16, 0, 0);
}

__device__ __forceinline__ u16 f2bf(float x) {
  union { float f; unsigned u; } c; c.f = x;
  unsigned u = c.u;
  u += 0x7fffu + ((u >> 16) & 1u);   // RNE; inputs finite randn
  return (u16)(u >> 16);
}

__device__ __forceinline__ void topk_update(float v, float best[TOPK]) {
  if (v < best[TOPK - 1]) {
    #pragma unroll
    for (int i = 0; i < TOPK; ++i) {
      float b = best[i];
      best[i] = fminf(b, v);
      v = fmaxf(b, v);
    }
  }
}

// ---- Kernel 1: fp32 -> bf16 convert + fp32 row norms; mb norms scattered into
//      MFMA-C-layout permuted order so the GEMM epilogue reads them as broadcasts.
__global__ __launch_bounds__(256) void prep_kernel(
    const float* __restrict__ fv, const float* __restrict__ mb,
    u16* __restrict__ fvb, u16* __restrict__ mbb,
    float* __restrict__ nf, float* __restrict__ nm_perm)
{
  int idx = blockIdx.x * 4 + (threadIdx.x >> 6);   // one wave per row
  int l = threadIdx.x & 63;
  const float* src; u16* dst;
  if (idx < M_ROWS) {
    src = fv + (size_t)idx * KDIM; dst = fvb + (size_t)idx * KDIM;
  } else {
    int r = idx - M_ROWS;
    src = mb + (size_t)r * KDIM; dst = mbb + (size_t)r * KDIM;
  }
  float4 x0 = ((const float4*)src)[2 * l];
  float4 x1 = ((const float4*)src)[2 * l + 1];
  float s = x0.x * x0.x + x0.y * x0.y + x0.z * x0.z + x0.w * x0.w
          + x1.x * x1.x + x1.y * x1.y + x1.z * x1.z + x1.w * x1.w;
  uint4 o;
  o.x = (unsigned)f2bf(x0.x) | ((unsigned)f2bf(x0.y) << 16);
  o.y = (unsigned)f2bf(x0.z) | ((unsigned)f2bf(x0.w) << 16);
  o.z = (unsigned)f2bf(x1.x) | ((unsigned)f2bf(x1.y) << 16);
  o.w = (unsigned)f2bf(x1.z) | ((unsigned)f2bf(x1.w) << 16);
  ((uint4*)dst)[l] = o;
  #pragma unroll
  for (int off = 32; off > 0; off >>= 1) s += __shfl_down(s, off, 64);
  if (l == 0) {
    if (idx < M_ROWS) {
      nf[idx] = s;
    } else {
      // 32x32 C/D: within-tile row w5 = (r&3) + 8*(r>>2) + 4*h  ->  [tile][h][r]
      int n  = idx - M_ROWS;
      int ig = n >> 5;            // global 32-row tile index (512 tiles)
      int w5 = n & 31;
      int h  = (w5 >> 2) & 1;
      int r  = (w5 & 3) | ((w5 >> 3) << 2);
      nm_perm[(ig * 2 + h) * 16 + r] = s;
    }
  }
}

// ---- Kernel 2: bf16 32x32x16 MFMA GEMM (swapped operands) + per-thread top-9 ----
// grid (64, 8), block 256 (4 waves). Block: 128 fv-rows (m) x 2048 mb-rows (n).
// Wave w owns m-strip w*32..w*32+31; lane's col m = strip + (l&31) -> ONE top-9 list.
// C[row=n][col=m]. Ranked v = nm[n] - 2*dot (nf[m] deferred to merge).
// LDS XOR-swizzle: 16B chunk c of row r stored at chunk c^(r&7); staging permutes
// the per-lane SOURCE k-offset (bijection per row), frag reads XOR the chunk.
// R1/R3 post-mortem: un-swizzled b128 frag reads were ~8-way bank-conflicted
// (row stride 128 B => all lanes on one 4-bank group) -> ~500 us LDS-bound floor.
__global__ __launch_bounds__(256) void gemm_topk_kernel(
    const u16* __restrict__ fvb, const u16* __restrict__ mbb,
    const float* __restrict__ nm_perm, float* __restrict__ partial)
{
  __shared__ __align__(16) u16 As[BM * BK];     // fv tile [128][64], 16 KB
  __shared__ __align__(16) u16 Bs[BN * BK];     // mb tile [128][64], 16 KB

  const int t   = threadIdx.x;
  const int l   = t & 63;
  const int w   = t >> 6;
  const int h   = l >> 5;        // half-wave
  const int c31 = l & 31;
  const int cx  = c31 & 7;       // frag-read row&7 (both As strip and Bs tiles)

  const int m0    = blockIdx.x * BM;
  const int ncoff = blockIdx.y * NPER;

  // staging: lane l covers row (base + l>>3), chunk l&7; source chunk swizzled
  const int srow_lo = l >> 3;                    // 0..7
  const int sc      = ((l & 7) ^ srow_lo) * 8;   // swizzled source k-offset (u16)

  float best[TOPK];
  #pragma unroll
  for (int i = 0; i < TOPK; ++i) best[i] = 3.4e38f;
  float T = 3.4e38f;

  for (int nt = 0; nt < NPER / BN; ++nt) {
    const int nbase = ncoff + nt * BN;
    f32x16 acc[4];
    #pragma unroll
    for (int i = 0; i < 4; ++i)
      #pragma unroll
      for (int r = 0; r < 16; ++r) acc[i][r] = 0.0f;

    for (int kc = 0; kc < KDIM / BK; ++kc) {
      __syncthreads();
      const int kb = kc * BK + sc;
      #pragma unroll
      for (int i = 0; i < 4; ++i) {
        gload_lds16(fvb + (size_t)(m0 + w * 32 + i * 8 + srow_lo) * KDIM + kb,
                    &As[(w * 32 + i * 8) * BK]);
        gload_lds16(mbb + (size_t)(nbase + w * 32 + i * 8 + srow_lo) * KDIM + kb,
                    &Bs[(w * 32 + i * 8) * BK]);
      }
      __syncthreads();
      #pragma unroll
      for (int kk = 0; kk < 4; ++kk) {
        const int ch = ((kk * 2 + h) ^ cx) * 8;              // swizzled chunk (u16)
        bf16x8 fvf = *(const bf16x8*)&As[(w * 32 + c31) * BK + ch];  // B-operand (m)
        #pragma unroll
        for (int i = 0; i < 4; ++i) {
          bf16x8 mbf = *(const bf16x8*)&Bs[(i * 32 + c31) * BK + ch]; // A-operand (n)
          acc[i] = __builtin_amdgcn_mfma_f32_32x32x16_bf16(mbf, fvf, acc[i], 0, 0, 0);
        }
      }
    }

    // ---- register epilogue: one list per thread; nm in permuted broadcast order ----
    #pragma unroll
    for (int i = 0; i < 4; ++i) {
      const float4* np = (const float4*)&nm_perm[(((nbase >> 5) + i) * 2 + h) * 16];
      float v[16];
      float bmin = 3.4e38f;
      #pragma unroll
      for (int rr = 0; rr < 4; ++rr) {
        float4 q = np[rr];
        v[rr * 4 + 0] = fmaf(-2.0f, acc[i][rr * 4 + 0], q.x);
        v[rr * 4 + 1] = fmaf(-2.0f, acc[i][rr * 4 + 1], q.y);
        v[rr * 4 + 2] = fmaf(-2.0f, acc[i][rr * 4 + 2], q.z);
        v[rr * 4 + 3] = fmaf(-2.0f, acc[i][rr * 4 + 3], q.w);
      }
      #pragma unroll
      for (int r = 0; r < 16; ++r) bmin = fminf(bmin, v[r]);
      if (bmin < T) {
        #pragma unroll
        for (int r = 0; r < 16; ++r) topk_update(v[r], best);
      }
    }
    T = fminf(best[TOPK - 1], __shfl_xor(best[TOPK - 1], 32, 64));
  }

  // merge the lane pair sharing this m-col (snapshot partner list, then insert)
  {
    float tmp[TOPK];
    #pragma unroll
    for (int s = 0; s < TOPK; ++s) tmp[s] = __shfl_xor(best[s], 32, 64);
    #pragma unroll
    for (int s = 0; s < TOPK; ++s) topk_update(tmp[s], best);
  }
  int m = m0 + w * 32 + c31;
  size_t base = ((size_t)blockIdx.y * M_ROWS + m) * TOPK;
  if (h == 0) {
    #pragma unroll
    for (int s = 0; s < 5; ++s) partial[base + s] = best[s];
  } else {
    #pragma unroll
    for (int s = 5; s < TOPK; ++s) partial[base + s] = best[s];
  }
}

// ---------------- Kernel 3: merge 8 partial lists/row, sqrt, pixel scores ----------------
__global__ __launch_bounds__(256) void merge_kernel(
    const float* __restrict__ partial, const float* __restrict__ nf,
    float* __restrict__ final9, float* __restrict__ out_pix)
{
  int row = blockIdx.x * 256 + threadIdx.x;   // 8192 rows
  float best[TOPK];
  #pragma unroll
  for (int i = 0; i < TOPK; ++i) best[i] = 3.4e38f;
  for (int s = 0; s < NCHUNKS; ++s) {
    const float* p = &partial[((size_t)s * M_ROWS + row) * TOPK];
    #pragma unroll
    for (int i = 0; i < TOPK; ++i) topk_update(p[i], best);
  }
  float nfr = nf[row];
  float d[TOPK];
  #pragma unroll
  for (int i = 0; i < TOPK; ++i) d[i] = sqrtf(fmaxf(best[i] + nfr, 0.0f));
  out_pix[row] = d[0];
  #pragma unroll
  for (int i = 0; i < TOPK; ++i) final9[(size_t)row * TOPK + i] = d[i];
}

// ---------------- Kernel 4: per-image argmax (first-max) + softmax score ----------------
__global__ __launch_bounds__(256) void img_kernel(
    const float* __restrict__ out_pix, const float* __restrict__ final9,
    const int* __restrict__ bptr, float* __restrict__ out_img)
{
  int img = blockIdx.x, t = threadIdx.x;
  float bv = -1.0f; int bi = 0;
  for (int p = t; p < 1024; p += 256) {
    float v = out_pix[img * 1024 + p];
    if (v > bv) { bv = v; bi = p; }
  }
  __shared__ float sv[256];
  __shared__ int   si[256];
  sv[t] = bv; si[t] = bi;
  __syncthreads();
  for (int off = 128; off > 0; off >>= 1) {
    if (t < off) {
      float v2 = sv[t + off]; int i2 = si[t + off];
      if (v2 > sv[t] || (v2 == sv[t] && i2 < si[t])) { sv[t] = v2; si[t] = i2; }
    }
    __syncthreads();
  }
  if (t == 0) {
    int row = img * 1024 + si[0];
    int b = bptr[0];
    float s0 = final9[(size_t)row * TOPK + 0];
    float score = s0;
    if (b > 1) {
      int bb = b < TOPK ? b : TOPK;
      float mx = s0;
      for (int i = 1; i < bb; ++i) mx = fmaxf(mx, final9[(size_t)row * TOPK + i]);
      float den = 0.0f;
      for (int i = 0; i < bb; ++i) den += expf(final9[(size_t)row * TOPK + i] - mx);
      score = s0 * (1.0f - expf(s0 - mx) / den);
    }
    out_img[img] = score;
  }
}

extern "C" void kernel_launch(void* const* d_in, const int* in_sizes, int n_in,
                              void* d_out, int out_size, void* d_ws, size_t ws_size,
                              hipStream_t stream) {
  const float* fv   = (const float*)d_in[0];
  const float* mb   = (const float*)d_in[1];
  const int*   bptr = (const int*)d_in[2];
  float* out = (float*)d_out;

  char* w = (char*)d_ws;
  u16*   fvb     = (u16*)w;                        // 8388608 B
  u16*   mbb     = (u16*)(w + 8388608);            // 16777216 B
  float* nf      = (float*)(w + 25165824);         // 32768 B
  float* nm_perm = (float*)(w + 25198592);         // 65536 B
  float* partial = (float*)(w + 25264128);         // 8*8192*9*4 = 2359296 B
  float* final9  = (float*)(w + 27623424);         // 294912 B   (end ~27.9 MB)

  hipLaunchKernelGGL(prep_kernel, dim3((M_ROWS + N_ROWS) / 4), dim3(256), 0, stream,
                     fv, mb, fvb, mbb, nf, nm_perm);
  hipLaunchKernelGGL(gemm_topk_kernel, dim3(M_ROWS / BM, NCHUNKS), dim3(256), 0, stream,
                     fvb, mbb, nm_perm, partial);
  hipLaunchKernelGGL(merge_kernel, dim3(M_ROWS / 256), dim3(256), 0, stream,
                     partial, nf, final9, out);
  hipLaunchKernelGGL(img_kernel, dim3(8), dim3(256), 0, stream,
                     out, final9, bptr, out + M_ROWS);
}